// Round 4
// baseline (211.815 us; speedup 1.0000x reference)
//
#include <hip/hip_runtime.h>
#include <hip/hip_bf16.h>

#define IMG_W 224
#define NPIX (IMG_W * IMG_W)
#define FOCAL 500.0f

// === Round-3 ledger ===
// R2 measured: project 95us, WRITE 66.9MB (~2.17M atomics x 32B beyond-L2 RMW),
//              FETCH 23.6MB, VALUBusy 5%, HBM 12% -> atomic-path bound.
// R3 change: monotone-safe test-and-test-and-set filter before atomicMin.
//   Safe under staleness: zbuf only decreases, so stale >= current;
//   skip when my_depth >= stale  =>  my_depth >= current  => can't improve.
// Predict: WRITE < 10MB, project dur 25-55us. If unchanged -> filter reads
// served stale from L2 -> round 4 goes to binning/privatization.

typedef float f4 __attribute__((ext_vector_type(4)));

__global__ void __launch_bounds__(256) project_kernel(
    const float* __restrict__ pc,       // (N,3)
    const float* __restrict__ cam_pos,  // (3,)
    const float* __restrict__ cam_rot,  // (3,3) row-major
    unsigned long long* __restrict__ zbuf,
    int n)                              // number of points
{
    const float cx = cam_pos[0], cy = cam_pos[1], cz = cam_pos[2];
    const float r00 = cam_rot[0], r01 = cam_rot[1], r02 = cam_rot[2];
    const float r10 = cam_rot[3], r11 = cam_rot[4], r12 = cam_rot[5];
    const float r20 = cam_rot[6], r21 = cam_rot[7], r22 = cam_rot[8];

    const int tid = blockIdx.x * blockDim.x + threadIdx.x;
    const int base = tid * 4;              // 4 points per thread
    if (base >= n) return;

    float px[4], py[4], pz[4];
    int cnt;
    if (base + 4 <= n) {
        // 48 B = 3 x float4 (16B aligned). Non-temporal: read-once stream.
        const f4* pc4 = reinterpret_cast<const f4*>(pc) + (size_t)tid * 3;
        f4 a = __builtin_nontemporal_load(pc4 + 0);
        f4 b = __builtin_nontemporal_load(pc4 + 1);
        f4 c = __builtin_nontemporal_load(pc4 + 2);
        px[0] = a.x; py[0] = a.y; pz[0] = a.z;
        px[1] = a.w; py[1] = b.x; pz[1] = b.y;
        px[2] = b.z; py[2] = b.w; pz[2] = c.x;
        px[3] = c.y; py[3] = c.z; pz[3] = c.w;
        cnt = 4;
    } else {
        cnt = n - base;
        for (int k = 0; k < cnt; ++k) {
            px[k] = pc[(size_t)(base + k) * 3 + 0];
            py[k] = pc[(size_t)(base + k) * 3 + 1];
            pz[k] = pc[(size_t)(base + k) * 3 + 2];
        }
    }

    // Phase 1: compute candidates (no memory ops) so the filter loads below
    // can all issue back-to-back and overlap their latency.
    unsigned dbits[4];
    int pid[4];
    unsigned idx[4];
    bool ok[4];
    #pragma unroll
    for (int k = 0; k < 4; ++k) {
        ok[k] = false;
        if (k >= cnt) continue;
        const float dx = px[k] - cx, dy = py[k] - cy, dz = pz[k] - cz;
        const float zc = r20 * dx + r21 * dy + r22 * dz;
        if (!(zc > 0.1f)) continue;
        const float xc = r00 * dx + r01 * dy + r02 * dz;
        const float yc = r10 * dx + r11 * dy + r12 * dz;
        const float inv = FOCAL / zc;
        const float x = xc * inv + (float)(IMG_W / 2);
        const float y = yc * inv + (float)(IMG_W / 2);
        if (!(x >= 0.0f && x < (float)IMG_W && y >= 0.0f && y < (float)IMG_W))
            continue;
        pid[k]   = (int)y * IMG_W + (int)x;
        dbits[k] = __float_as_uint(zc);
        idx[k]   = (unsigned)(base + k);
        ok[k]    = true;
    }

    // Phase 2: filter loads (depth half = high u32 of the little-endian u64).
    // Agent-scope relaxed load reads the same coherence point the atomics
    // write, so it's as fresh as the HW provides; correctness needs only
    // monotonicity, not freshness.
    const unsigned* zb32 = reinterpret_cast<const unsigned*>(zbuf);
    unsigned seen[4];
    #pragma unroll
    for (int k = 0; k < 4; ++k) {
        if (ok[k])
            seen[k] = __hip_atomic_load(&zb32[2 * pid[k] + 1],
                                        __ATOMIC_RELAXED, __HIP_MEMORY_SCOPE_AGENT);
    }

    // Phase 3: atomic only when strictly improving.
    #pragma unroll
    for (int k = 0; k < 4; ++k) {
        if (ok[k] && dbits[k] < seen[k]) {
            const unsigned long long pk =
                ((unsigned long long)dbits[k] << 32) | idx[k];
            atomicMin(&zbuf[pid[k]], pk);
        }
    }
}

// Pass 2: per pixel, gather winner color, write CHW float32 image.
__global__ void __launch_bounds__(256) resolve_kernel(
    const unsigned long long* __restrict__ zbuf,
    const float* __restrict__ colors,   // (N,3)
    float* __restrict__ out)            // (3, 224, 224) flattened
{
    const int p = blockIdx.x * blockDim.x + threadIdx.x;
    if (p >= NPIX) return;
    const unsigned long long pk = zbuf[p];
    float r = 0.0f, g = 0.0f, b = 0.0f;
    if (pk != ~0ULL) {
        const unsigned idx = (unsigned)(pk & 0xFFFFFFFFu);
        r = colors[(size_t)idx * 3 + 0];
        g = colors[(size_t)idx * 3 + 1];
        b = colors[(size_t)idx * 3 + 2];
    }
    out[0 * NPIX + p] = r;
    out[1 * NPIX + p] = g;
    out[2 * NPIX + p] = b;
}

extern "C" void kernel_launch(void* const* d_in, const int* in_sizes, int n_in,
                              void* d_out, int out_size, void* d_ws, size_t ws_size,
                              hipStream_t stream)
{
    const float* pc      = (const float*)d_in[0];  // point_cloud (N,3)
    const float* cam_pos = (const float*)d_in[1];  // (3,)
    const float* cam_rot = (const float*)d_in[2];  // (3,3)
    const float* colors  = (const float*)d_in[3];  // (N,3)
    float* out = (float*)d_out;

    const int n = in_sizes[0] / 3;  // number of points

    unsigned long long* zbuf = (unsigned long long*)d_ws;  // NPIX * 8 bytes

    hipMemsetAsync(zbuf, 0xFF, (size_t)NPIX * sizeof(unsigned long long), stream);

    const int threads = 256;
    const int nThreads = (n + 3) / 4;                     // 4 points/thread
    const int blocks = (nThreads + threads - 1) / threads;
    project_kernel<<<blocks, threads, 0, stream>>>(pc, cam_pos, cam_rot, zbuf, n);

    const int pblocks = (NPIX + threads - 1) / threads;
    resolve_kernel<<<pblocks, threads, 0, stream>>>(zbuf, colors, out);
}

// Round 5
// 195.301 us; speedup vs baseline: 1.0846x; 1.0846x over previous
//
#include <hip/hip_runtime.h>
#include <hip/hip_bf16.h>

#define IMG_W 224
#define NPIX (IMG_W * IMG_W)
#define FOCAL 500.0f
#define NREP 8

// === Round-4 ledger ===
// Measured ceiling: ~23 scattered beyond-L2 transactions per ns, regardless of
// type (R2: 2.17M atomics/95us; R4: 2.7M mixed/113us). HBM 11%, VALU 6%.
// R5 change: per-XCD L2-resident zbuf replicas. Plain (no-sc1) atomicMin is
// serviced in the local XCD's L2; replica[x] is written ONLY by waves whose
// s_getreg(HW_REG_XCC_ID)==x, so that L2 is the single serialization point ->
// coherent without device scope. Resolve min-reduces the 8 replicas (plain
// loads; kernel-end flush guarantees visibility).
// Predict: project 12-25us, WRITE ~4MB, FETCH ~26MB.
// Falsifiers: dur~95 & WRITE~67MB -> scope routed to LLC anyway;
//             absmax>0 -> within-XCD L2 atomic coherence wrong; revert+bin.

typedef float f4 __attribute__((ext_vector_type(4)));

__device__ __forceinline__ unsigned xcc_id() {
    unsigned x;
    asm volatile("s_getreg_b32 %0, hwreg(HW_REG_XCC_ID)" : "=s"(x));
    return x & (NREP - 1);
}

__global__ void __launch_bounds__(256) project_kernel(
    const float* __restrict__ pc,       // (N,3)
    const float* __restrict__ cam_pos,  // (3,)
    const float* __restrict__ cam_rot,  // (3,3) row-major
    unsigned long long* __restrict__ rep,  // NREP x NPIX (or 1 x NPIX fallback)
    int n, int use_rep)
{
    const float cx = cam_pos[0], cy = cam_pos[1], cz = cam_pos[2];
    const float r00 = cam_rot[0], r01 = cam_rot[1], r02 = cam_rot[2];
    const float r10 = cam_rot[3], r11 = cam_rot[4], r12 = cam_rot[5];
    const float r20 = cam_rot[6], r21 = cam_rot[7], r22 = cam_rot[8];

    const int tid = blockIdx.x * blockDim.x + threadIdx.x;
    const int base = tid * 4;              // 4 points per thread
    if (base >= n) return;

    float px[4], py[4], pz[4];
    int cnt;
    if (base + 4 <= n) {
        // 48 B = 3 x float4 (16B aligned). Non-temporal read-once stream.
        const f4* pc4 = reinterpret_cast<const f4*>(pc) + (size_t)tid * 3;
        f4 a = __builtin_nontemporal_load(pc4 + 0);
        f4 b = __builtin_nontemporal_load(pc4 + 1);
        f4 c = __builtin_nontemporal_load(pc4 + 2);
        px[0] = a.x; py[0] = a.y; pz[0] = a.z;
        px[1] = a.w; py[1] = b.x; pz[1] = b.y;
        px[2] = b.z; py[2] = b.w; pz[2] = c.x;
        px[3] = c.y; py[3] = c.z; pz[3] = c.w;
        cnt = 4;
    } else {
        cnt = n - base;
        for (int k = 0; k < cnt; ++k) {
            px[k] = pc[(size_t)(base + k) * 3 + 0];
            py[k] = pc[(size_t)(base + k) * 3 + 1];
            pz[k] = pc[(size_t)(base + k) * 3 + 2];
        }
    }

    // wave-uniform replica base: this wave's physical XCD owns its replica
    unsigned long long* buf = rep;
    if (use_rep) buf += (size_t)xcc_id() * NPIX;

    #pragma unroll
    for (int k = 0; k < 4; ++k) {
        if (k >= cnt) break;
        const float dx = px[k] - cx, dy = py[k] - cy, dz = pz[k] - cz;
        const float zc = r20 * dx + r21 * dy + r22 * dz;
        if (!(zc > 0.1f)) continue;                       // valid = z > 0.1
        const float xc = r00 * dx + r01 * dy + r02 * dz;
        const float yc = r10 * dx + r11 * dy + r12 * dz;
        const float inv = FOCAL / zc;
        const float x = xc * inv + (float)(IMG_W / 2);
        const float y = yc * inv + (float)(IMG_W / 2);
        if (!(x >= 0.0f && x < (float)IMG_W && y >= 0.0f && y < (float)IMG_W))
            continue;
        const int pid = (int)y * IMG_W + (int)x;
        const unsigned long long pk =
            ((unsigned long long)__float_as_uint(zc) << 32) |
            (unsigned int)(base + k);
        if (use_rep) {
            // no sc bits -> RMW at this XCD's L2 (replica is L2-resident)
            __hip_atomic_fetch_min(&buf[pid], pk,
                                   __ATOMIC_RELAXED, __HIP_MEMORY_SCOPE_WORKGROUP);
        } else {
            atomicMin(&buf[pid], pk);     // device scope fallback
        }
    }
}

// Resolve: min over replicas per pixel, gather winner color, write CHW image.
__global__ void __launch_bounds__(256) resolve_kernel(
    const unsigned long long* __restrict__ rep,
    const float* __restrict__ colors,   // (N,3)
    float* __restrict__ out,            // (3, 224, 224)
    int nrep)
{
    const int p = blockIdx.x * blockDim.x + threadIdx.x;
    if (p >= NPIX) return;
    unsigned long long m = ~0ULL;
    for (int r = 0; r < nrep; ++r) {
        const unsigned long long v = rep[(size_t)r * NPIX + p];
        m = v < m ? v : m;
    }
    float cr = 0.0f, cg = 0.0f, cb = 0.0f;
    if (m != ~0ULL) {
        const unsigned idx = (unsigned)(m & 0xFFFFFFFFu);
        cr = colors[(size_t)idx * 3 + 0];
        cg = colors[(size_t)idx * 3 + 1];
        cb = colors[(size_t)idx * 3 + 2];
    }
    out[0 * NPIX + p] = cr;
    out[1 * NPIX + p] = cg;
    out[2 * NPIX + p] = cb;
}

extern "C" void kernel_launch(void* const* d_in, const int* in_sizes, int n_in,
                              void* d_out, int out_size, void* d_ws, size_t ws_size,
                              hipStream_t stream)
{
    const float* pc      = (const float*)d_in[0];  // point_cloud (N,3)
    const float* cam_pos = (const float*)d_in[1];  // (3,)
    const float* cam_rot = (const float*)d_in[2];  // (3,3)
    const float* colors  = (const float*)d_in[3];  // (N,3)
    float* out = (float*)d_out;

    const int n = in_sizes[0] / 3;

    unsigned long long* rep = (unsigned long long*)d_ws;
    const int nrep = (ws_size >= (size_t)NREP * NPIX * 8) ? NREP : 1;
    const int use_rep = (nrep == NREP) ? 1 : 0;

    hipMemsetAsync(rep, 0xFF, (size_t)nrep * NPIX * sizeof(unsigned long long),
                   stream);

    const int threads = 256;
    const int nThreads = (n + 3) / 4;
    const int blocks = (nThreads + threads - 1) / threads;
    project_kernel<<<blocks, threads, 0, stream>>>(pc, cam_pos, cam_rot, rep,
                                                   n, use_rep);

    const int pblocks = (NPIX + threads - 1) / threads;
    resolve_kernel<<<pblocks, threads, 0, stream>>>(rep, colors, out, nrep);
}

// Round 8
// 195.143 us; speedup vs baseline: 1.0854x; 1.0008x over previous
//
#include <hip/hip_runtime.h>
#include <hip/hip_bf16.h>

#define IMG_W 224
#define NPIX (IMG_W * IMG_W)
#define FOCAL 500.0f
#define NREP 8

// === Round-8 ledger ===
// Known: ws >= 401KB (R2-R4 ran) and ws < 3.21MB (R5 silent fallback).
// Ceiling: ~23 beyond-L2 scattered transactions/ns; device atomics write
// through to HBM (WRITE 67MB = 2.17M x 32B on a 400KB buffer).
// Hypothesis: workgroup-scope (no sc1) atomicMin is serviced in the local
// XCD's L2; per-XCD single-writer replicas make that coherent.
// This round: Path B footprint cut to 1.605MB (in-place reduce into rep 0)
// so the replica experiment survives a ~2MB-ish ws. Distinct kernel names.
// Predict rep32: project 10-20us + winner 10-18us, WRITE ~3MB, FETCH ~50MB.
// Falsifier: rep32 at ~95us / WRITE ~67MB -> scope routes far anyway -> bin.
// Filter path: 40-95us / WRITE 15-67MB (stale-snapshot effectiveness test).

typedef float f4 __attribute__((ext_vector_type(4)));

__device__ __forceinline__ unsigned xcc_id() {
    unsigned x;
    asm volatile("s_getreg_b32 %0, hwreg(HW_REG_XCC_ID)" : "=s"(x));
    return x & (NREP - 1);
}

// Shared projection: compute up to 4 candidates for this thread.
__device__ __forceinline__ int project4(
    const float* __restrict__ pc, int n, int tid,
    const float* __restrict__ cam_pos, const float* __restrict__ cam_rot,
    unsigned dbits[4], int pid[4], unsigned idx[4], bool ok[4])
{
    const float cx = cam_pos[0], cy = cam_pos[1], cz = cam_pos[2];
    const float r00 = cam_rot[0], r01 = cam_rot[1], r02 = cam_rot[2];
    const float r10 = cam_rot[3], r11 = cam_rot[4], r12 = cam_rot[5];
    const float r20 = cam_rot[6], r21 = cam_rot[7], r22 = cam_rot[8];

    const int base = tid * 4;
    if (base >= n) return 0;

    float px[4], py[4], pz[4];
    int cnt;
    if (base + 4 <= n) {
        const f4* pc4 = reinterpret_cast<const f4*>(pc) + (size_t)tid * 3;
        f4 a = __builtin_nontemporal_load(pc4 + 0);
        f4 b = __builtin_nontemporal_load(pc4 + 1);
        f4 c = __builtin_nontemporal_load(pc4 + 2);
        px[0] = a.x; py[0] = a.y; pz[0] = a.z;
        px[1] = a.w; py[1] = b.x; pz[1] = b.y;
        px[2] = b.z; py[2] = b.w; pz[2] = c.x;
        px[3] = c.y; py[3] = c.z; pz[3] = c.w;
        cnt = 4;
    } else {
        cnt = n - base;
        for (int k = 0; k < cnt; ++k) {
            px[k] = pc[(size_t)(base + k) * 3 + 0];
            py[k] = pc[(size_t)(base + k) * 3 + 1];
            pz[k] = pc[(size_t)(base + k) * 3 + 2];
        }
    }

    #pragma unroll
    for (int k = 0; k < 4; ++k) {
        ok[k] = false;
        if (k >= cnt) continue;
        const float dx = px[k] - cx, dy = py[k] - cy, dz = pz[k] - cz;
        const float zc = r20 * dx + r21 * dy + r22 * dz;
        if (!(zc > 0.1f)) continue;
        const float xc = r00 * dx + r01 * dy + r02 * dz;
        const float yc = r10 * dx + r11 * dy + r12 * dz;
        const float inv = FOCAL / zc;
        const float x = xc * inv + (float)(IMG_W / 2);
        const float y = yc * inv + (float)(IMG_W / 2);
        if (!(x >= 0.0f && x < (float)IMG_W && y >= 0.0f && y < (float)IMG_W))
            continue;
        pid[k]   = (int)y * IMG_W + (int)x;
        dbits[k] = __float_as_uint(zc);
        idx[k]   = (unsigned)(base + k);
        ok[k]    = true;
    }
    return cnt;
}

// ---- Path A: 8x u64 replicas, workgroup-scope atomics (needs 3.21MB) ----
__global__ void __launch_bounds__(256) project_rep64(
    const float* __restrict__ pc, const float* __restrict__ cam_pos,
    const float* __restrict__ cam_rot,
    unsigned long long* __restrict__ rep, int n)
{
    const int tid = blockIdx.x * blockDim.x + threadIdx.x;
    unsigned dbits[4]; int pid[4]; unsigned idx[4]; bool ok[4];
    if (project4(pc, n, tid, cam_pos, cam_rot, dbits, pid, idx, ok) == 0) return;
    unsigned long long* buf = rep + (size_t)xcc_id() * NPIX;
    #pragma unroll
    for (int k = 0; k < 4; ++k)
        if (ok[k]) {
            const unsigned long long pk =
                ((unsigned long long)dbits[k] << 32) | idx[k];
            __hip_atomic_fetch_min(&buf[pid[k]], pk,
                                   __ATOMIC_RELAXED, __HIP_MEMORY_SCOPE_WORKGROUP);
        }
}

__global__ void __launch_bounds__(256) resolve_rep64(
    const unsigned long long* __restrict__ rep,
    const float* __restrict__ colors, float* __restrict__ out)
{
    const int p = blockIdx.x * blockDim.x + threadIdx.x;
    if (p >= NPIX) return;
    unsigned long long m = ~0ULL;
    #pragma unroll
    for (int r = 0; r < NREP; ++r) {
        const unsigned long long v = rep[(size_t)r * NPIX + p];
        m = v < m ? v : m;
    }
    float cr = 0.0f, cg = 0.0f, cb = 0.0f;
    if (m != ~0ULL) {
        const unsigned idx = (unsigned)(m & 0xFFFFFFFFu);
        cr = colors[(size_t)idx * 3 + 0];
        cg = colors[(size_t)idx * 3 + 1];
        cb = colors[(size_t)idx * 3 + 2];
    }
    out[0 * NPIX + p] = cr;
    out[1 * NPIX + p] = cg;
    out[2 * NPIX + p] = cb;
}

// ---- Path B: 8x u32 depth replicas + winner re-pass (needs 1.605MB) ----
__global__ void __launch_bounds__(256) project_rep32(
    const float* __restrict__ pc, const float* __restrict__ cam_pos,
    const float* __restrict__ cam_rot,
    unsigned* __restrict__ rep32, int n)
{
    const int tid = blockIdx.x * blockDim.x + threadIdx.x;
    unsigned dbits[4]; int pid[4]; unsigned idx[4]; bool ok[4];
    if (project4(pc, n, tid, cam_pos, cam_rot, dbits, pid, idx, ok) == 0) return;
    unsigned* buf = rep32 + (size_t)xcc_id() * NPIX;
    #pragma unroll
    for (int k = 0; k < 4; ++k)
        if (ok[k])
            __hip_atomic_fetch_min(&buf[pid[k]], dbits[k],
                                   __ATOMIC_RELAXED, __HIP_MEMORY_SCOPE_WORKGROUP);
}

// In-place: min over the 8 replicas lands in replica 0 (each thread owns
// exactly pixel p: reads r*NPIX+p, writes p — no cross-thread hazard).
__global__ void __launch_bounds__(256) reduce_min32(unsigned* __restrict__ rep32)
{
    const int p = blockIdx.x * blockDim.x + threadIdx.x;
    if (p >= NPIX) return;
    unsigned m = 0xFFFFFFFFu;
    #pragma unroll
    for (int r = 0; r < NREP; ++r) {
        const unsigned v = rep32[(size_t)r * NPIX + p];
        m = v < m ? v : m;
    }
    rep32[p] = m;   // 0xFFFFFFFF (NaN bits) = empty; never equals finite depth
}

__global__ void __launch_bounds__(256) winner32(
    const float* __restrict__ pc, const float* __restrict__ cam_pos,
    const float* __restrict__ cam_rot,
    const unsigned* __restrict__ minbuf,   // = rep32 replica 0
    const float* __restrict__ colors, float* __restrict__ out, int n)
{
    const int tid = blockIdx.x * blockDim.x + threadIdx.x;
    unsigned dbits[4]; int pid[4]; unsigned idx[4]; bool ok[4];
    if (project4(pc, n, tid, cam_pos, cam_rot, dbits, pid, idx, ok) == 0) return;
    #pragma unroll
    for (int k = 0; k < 4; ++k) {
        if (ok[k] && dbits[k] == minbuf[pid[k]]) {
            const float* c = colors + (size_t)idx[k] * 3;
            out[0 * NPIX + pid[k]] = c[0];
            out[1 * NPIX + pid[k]] = c[1];
            out[2 * NPIX + pid[k]] = c[2];
        }
    }
}

// ---- Path C: single zbuf + plain-load monotone filter (401KB) ----
__global__ void __launch_bounds__(256) project_filter(
    const float* __restrict__ pc, const float* __restrict__ cam_pos,
    const float* __restrict__ cam_rot,
    unsigned long long* __restrict__ zbuf, int n)
{
    const int tid = blockIdx.x * blockDim.x + threadIdx.x;
    unsigned dbits[4]; int pid[4]; unsigned idx[4]; bool ok[4];
    if (project4(pc, n, tid, cam_pos, cam_rot, dbits, pid, idx, ok) == 0) return;

    const unsigned* zb32 = reinterpret_cast<const unsigned*>(zbuf);
    unsigned seen[4];
    #pragma unroll
    for (int k = 0; k < 4; ++k)
        if (ok[k]) seen[k] = zb32[2 * pid[k] + 1];   // plain cached load
                                                      // stale>=current: safe
    #pragma unroll
    for (int k = 0; k < 4; ++k)
        if (ok[k] && dbits[k] < seen[k]) {
            const unsigned long long pk =
                ((unsigned long long)dbits[k] << 32) | idx[k];
            atomicMin(&zbuf[pid[k]], pk);
        }
}

__global__ void __launch_bounds__(256) resolve_single(
    const unsigned long long* __restrict__ zbuf,
    const float* __restrict__ colors, float* __restrict__ out)
{
    const int p = blockIdx.x * blockDim.x + threadIdx.x;
    if (p >= NPIX) return;
    const unsigned long long m = zbuf[p];
    float cr = 0.0f, cg = 0.0f, cb = 0.0f;
    if (m != ~0ULL) {
        const unsigned idx = (unsigned)(m & 0xFFFFFFFFu);
        cr = colors[(size_t)idx * 3 + 0];
        cg = colors[(size_t)idx * 3 + 1];
        cb = colors[(size_t)idx * 3 + 2];
    }
    out[0 * NPIX + p] = cr;
    out[1 * NPIX + p] = cg;
    out[2 * NPIX + p] = cb;
}

extern "C" void kernel_launch(void* const* d_in, const int* in_sizes, int n_in,
                              void* d_out, int out_size, void* d_ws, size_t ws_size,
                              hipStream_t stream)
{
    const float* pc      = (const float*)d_in[0];
    const float* cam_pos = (const float*)d_in[1];
    const float* cam_rot = (const float*)d_in[2];
    const float* colors  = (const float*)d_in[3];
    float* out = (float*)d_out;

    const int n = in_sizes[0] / 3;
    const int threads = 256;
    const int blocks  = ((n + 3) / 4 + threads - 1) / threads;
    const int pblocks = (NPIX + threads - 1) / threads;

    const size_t needA = (size_t)NREP * NPIX * 8;   // 3.21 MB
    const size_t needB = (size_t)NREP * NPIX * 4;   // 1.605 MB

    if (ws_size >= needA) {
        unsigned long long* rep = (unsigned long long*)d_ws;
        hipMemsetAsync(rep, 0xFF, needA, stream);
        project_rep64<<<blocks, threads, 0, stream>>>(pc, cam_pos, cam_rot, rep, n);
        resolve_rep64<<<pblocks, threads, 0, stream>>>(rep, colors, out);
    } else if (ws_size >= needB) {
        unsigned* rep32 = (unsigned*)d_ws;
        hipMemsetAsync(rep32, 0xFF, needB, stream);
        hipMemsetAsync(out, 0, (size_t)NPIX * 3 * sizeof(float), stream);
        project_rep32<<<blocks, threads, 0, stream>>>(pc, cam_pos, cam_rot, rep32, n);
        reduce_min32<<<pblocks, threads, 0, stream>>>(rep32);
        winner32<<<blocks, threads, 0, stream>>>(pc, cam_pos, cam_rot, rep32,
                                                 colors, out, n);
    } else {
        unsigned long long* zbuf = (unsigned long long*)d_ws;
        hipMemsetAsync(zbuf, 0xFF, (size_t)NPIX * 8, stream);
        project_filter<<<blocks, threads, 0, stream>>>(pc, cam_pos, cam_rot, zbuf, n);
        resolve_single<<<pblocks, threads, 0, stream>>>(zbuf, colors, out);
    }
}